// Round 8
// baseline (386.531 us; speedup 1.0000x reference)
//
#include <hip/hip_runtime.h>
#include <hip/hip_bf16.h>
#include <stdint.h>

// B=4 S=2048 D=1024 H=2048 E=8 ; T = 8192 tokens, top-1 MoE.
// Inputs FLOAT32, output FLOAT32; GEMM compute in bf16 MFMA (fp32 accum).
// Round 14: R7 kept (64x64 GEMMs, swizzled transpose) + router and transpose
// FUSED into one prep_kernel (blocks 0-511 router, 512-8703 transpose) so the
// two independent preprocessing passes overlap instead of serializing
// (94us -> ~75us predicted). Router restructured to ~1/4 the Wr register
// cache (w[4][8] per i-chunk, identical summation order -> bit-identical)
// so the fused kernel's VGPR (~100) doesn't throttle transpose residency.

typedef unsigned short bf16_t;
typedef short short8 __attribute__((ext_vector_type(8)));
typedef float f32x4 __attribute__((ext_vector_type(4)));

#define T_TOK 8192
#define DDIM 1024
#define HDIM 2048
#define NEXP 8
#define MAXT64 136          // sum ceil(count_e/64) <= 8192/64 + 8 = 136
#define ROWSP (MAXT64 * 64) // 8704 padded row space

__device__ __forceinline__ bf16_t f2b(float f) {
    unsigned int x = __builtin_bit_cast(unsigned int, f);
    unsigned int r = x + 0x7fffu + ((x >> 16) & 1u);   // RNE
    return (bf16_t)(r >> 16);
}
__device__ __forceinline__ void gld_lds16(const bf16_t* src, bf16_t* dst) {
    // per-lane global src, wave-uniform LDS base; lane L writes at dst + L*16B
    __builtin_amdgcn_global_load_lds((const __attribute__((address_space(1))) void*)src,
                                     (__attribute__((address_space(3))) void*)dst, 16, 0, 0);
}

// ---------------- prep: router (blocks 0..511) + weight transpose (512..8703) ----------------
// Router: 4 tokens/wave, Wr cached 32 regs per i-chunk, fused x->bf16.
// Transpose: fp32->bf16 + transpose via XOR-swizzled LDS (involution swizzle,
// conflict-free-ish bank walks, register 4x4 transpose, coalesced writes).
__global__ __launch_bounds__(256) void prep_kernel(
    const float* __restrict__ x, const float* __restrict__ Wr,
    const float* __restrict__ br, int* __restrict__ expert_id,
    float* __restrict__ gate, int* __restrict__ counts,
    bf16_t* __restrict__ xbf,
    const float* __restrict__ W1, const float* __restrict__ W2,
    bf16_t* __restrict__ W1t, bf16_t* __restrict__ W2t) {
    __shared__ bf16_t tile[64][72];   // transpose staging (9216 B)
    __shared__ int hcnt[NEXP];
    int tid = threadIdx.x;

    if (blockIdx.x < 512) {
        // ---------------- router ----------------
        int wave = tid >> 6, lane = tid & 63;
        if (tid < NEXP) hcnt[tid] = 0;
        __syncthreads();

        float acc[4][NEXP];
#pragma unroll
        for (int tt = 0; tt < 4; tt++)
#pragma unroll
            for (int e = 0; e < NEXP; e++) acc[tt][e] = 0.f;

        int t0 = (blockIdx.x * 4 + wave) * 4;
#pragma unroll
        for (int i = 0; i < 4; i++) {
            float w[4][NEXP];   // this i-chunk's Wr rows for this lane
#pragma unroll
            for (int j = 0; j < 4; j++) {
                const float* p = Wr + (size_t)(i * 256 + lane * 4 + j) * NEXP;
                float4 a = *(const float4*)p;
                float4 b = *(const float4*)(p + 4);
                w[j][0] = a.x; w[j][1] = a.y; w[j][2] = a.z; w[j][3] = a.w;
                w[j][4] = b.x; w[j][5] = b.y; w[j][6] = b.z; w[j][7] = b.w;
            }
#pragma unroll
            for (int tt = 0; tt < 4; tt++) {
                int t = t0 + tt;
                const float* xp = x + (size_t)t * DDIM + i * 256 + lane * 4;
                float4 xv = *(const float4*)xp;
                bf16_t tmp[4] = {f2b(xv.x), f2b(xv.y), f2b(xv.z), f2b(xv.w)};
                *(uint2*)(xbf + (size_t)t * DDIM + i * 256 + lane * 4) = *(uint2*)tmp;
                float xs[4] = {xv.x, xv.y, xv.z, xv.w};
#pragma unroll
                for (int j = 0; j < 4; j++)
#pragma unroll
                    for (int e = 0; e < NEXP; e++) acc[tt][e] += xs[j] * w[j][e];
            }
        }
#pragma unroll
        for (int tt = 0; tt < 4; tt++) {
            float a8[NEXP];
#pragma unroll
            for (int e = 0; e < NEXP; e++) a8[e] = acc[tt][e];
#pragma unroll
            for (int off = 32; off; off >>= 1)
#pragma unroll
                for (int e = 0; e < NEXP; e++) a8[e] += __shfl_xor(a8[e], off);
            if (lane == 0) {
                int t = t0 + tt;
                float l[NEXP];
#pragma unroll
                for (int e = 0; e < NEXP; e++) l[e] = a8[e] + br[e];
                int best = 0; float bm = l[0];
#pragma unroll
                for (int e = 1; e < NEXP; e++) if (l[e] > bm) { bm = l[e]; best = e; }
                float s = 0.f;
#pragma unroll
                for (int e = 0; e < NEXP; e++) s += __expf(l[e] - bm);
                expert_id[t] = best;
                gate[t] = 1.0f / s;      // softmax prob of the argmax expert
                atomicAdd(&hcnt[best], 1);
            }
        }
        __syncthreads();
        if (tid < NEXP) atomicAdd(&counts[tid], hcnt[tid]);
        return;
    }

    // ---------------- weight transpose ----------------
    int bid = blockIdx.x - 512;
    int z = bid >> 9, bxy = bid & 511;
    const float* inp; bf16_t* outp; int R, C;
    if (z < 8) { inp = W1 + (size_t)z * DDIM * HDIM; outp = W1t + (size_t)z * DDIM * HDIM;
                 R = DDIM; C = HDIM; }
    else       { inp = W2 + (size_t)(z - 8) * HDIM * DDIM; outp = W2t + (size_t)(z - 8) * HDIM * DDIM;
                 R = HDIM; C = DDIM; }
    int ctiles = C >> 6;
    int cx = bxy % ctiles, ry = bxy / ctiles;
    int r0 = ry * 64, c0 = cx * 64;
#pragma unroll
    for (int v = tid; v < 1024; v += 256) {     // 64 rows x 16 chunks of 4 floats
        int r = v >> 4, ch = v & 15;
        float4 f = *(const float4*)(inp + (size_t)(r0 + r) * C + c0 + ch * 4);
        bf16_t tmp[4] = {f2b(f.x), f2b(f.y), f2b(f.z), f2b(f.w)};
        *(uint2*)&tile[r][(ch ^ (r & 15)) * 4] = *(uint2*)tmp;
    }
    __syncthreads();
    {
        int rb = tid & 15, cb = tid >> 4;       // 16x16 grid of 4x4 sub-blocks
        uint2 m[4];
#pragma unroll
        for (int i = 0; i < 4; i++) {
            int r = rb * 4 + i;
            m[i] = *(const uint2*)&tile[r][(cb ^ (r & 15)) * 4];
        }
        uint32_t w0[4] = {m[0].x, m[1].x, m[2].x, m[3].x};  // cols 0,1 of the 4 rows
        uint32_t w1[4] = {m[0].y, m[1].y, m[2].y, m[3].y};  // cols 2,3
#pragma unroll
        for (int j = 0; j < 4; j++) {
            const uint32_t* w = (j < 2) ? w0 : w1;
            uint32_t o0, o1;
            if (j & 1) { o0 = (w[0] >> 16) | (w[1] & 0xffff0000u);
                         o1 = (w[2] >> 16) | (w[3] & 0xffff0000u); }
            else       { o0 = (w[0] & 0xffffu) | (w[1] << 16);
                         o1 = (w[2] & 0xffffu) | (w[3] << 16); }
            uint2 o; o.x = o0; o.y = o1;
            *(uint2*)(outp + (size_t)(c0 + cb * 4 + j) * R + r0 + rb * 4) = o;
        }
    }
}

// ---------------- scan: 64-aligned segment offsets + 64-tile->expert map ----------------
__global__ __launch_bounds__(64) void scan_kernel(const int* __restrict__ counts,
                                                  int* __restrict__ pad_off,
                                                  int* __restrict__ tile_expert) {
    if (threadIdx.x == 0) {
        int rowoff = 0, t = 0;
        for (int e = 0; e < NEXP; e++) {
            pad_off[e] = rowoff;
            int nt = (counts[e] + 63) >> 6;
            rowoff += nt << 6;
            for (int i = 0; i < nt; i++) tile_expert[t++] = e;
        }
        while (t < MAXT64) tile_expert[t++] = -1;
    }
}

// ---------------- scatter: build row->token maps ----------------
__global__ __launch_bounds__(256) void scatter_kernel(
    const int* __restrict__ expert_id, const float* __restrict__ gate,
    const int* __restrict__ pad_off, int* __restrict__ cursor,
    int* __restrict__ tok_of_row, float* __restrict__ gate_of_row) {
    int t = blockIdx.x * 256 + threadIdx.x;
    int e = expert_id[t];
    int p = atomicAdd(&cursor[e], 1);
    int row = pad_off[e] + p;
    tok_of_row[row] = t;
    gate_of_row[row] = gate[t];
}

// ---------------- GEMM1: h[row][H] = relu(xbf[tok[row]] @ W1t[e]^T + b1[e]) ----------------
// 64x64 tile, 4 waves, each wave owns a 32x32 quadrant (acc 2x2). Single-buffer,
// XOR-swizzled LDS, R0 sync structure. W1t: [E][H][D]. grid (H/64, MAXT64).
__global__ __launch_bounds__(256) void gemm1_kernel(
    const bf16_t* __restrict__ x, const bf16_t* __restrict__ W1t,
    const float* __restrict__ b1, const int* __restrict__ tile_expert,
    const int* __restrict__ tok_of_row, bf16_t* __restrict__ hbuf) {
    constexpr int K = DDIM, N = HDIM;
    int tile_n = blockIdx.x, tile_m = blockIdx.y;
    int e = tile_expert[tile_m];
    if (e < 0) return;
    __shared__ bf16_t lA[64 * 64];   // 8 KiB
    __shared__ bf16_t lB[64 * 64];   // 8 KiB
    int tid = threadIdx.x, wave = tid >> 6, lane = tid & 63;
    // staging: lane L covers row (base + L>>3), fetches source chunk (L&7)^((L>>3)&7)
    int sc = (lane & 7) ^ ((lane >> 3) & 7);
    const bf16_t* asrc[2]; const bf16_t* bsrc[2];
#pragma unroll
    for (int c = 0; c < 2; c++) {
        int rr = wave * 16 + c * 8 + (lane >> 3);
        int tok = tok_of_row[tile_m * 64 + rr];
        if (tok < 0) tok = 0;   // padded row: read any valid row; masked downstream
        asrc[c] = x + (size_t)tok * K + sc * 8;
        bsrc[c] = W1t + (size_t)e * N * K + (size_t)(tile_n * 64 + rr) * K + sc * 8;
    }
    f32x4 acc[2][2];
#pragma unroll
    for (int i = 0; i < 2; i++)
#pragma unroll
        for (int j = 0; j < 2; j++) acc[i][j] = {0.f, 0.f, 0.f, 0.f};
    int wm = wave >> 1, wn = wave & 1;
    int lm = lane & 15, quad = lane >> 4;
    int sw = lm & 7;   // row&7 for all fragment rows (row = mult16 + lm)

    for (int k0 = 0; k0 < K; k0 += 64) {
        __syncthreads();
#pragma unroll
        for (int c = 0; c < 2; c++) {
            gld_lds16(asrc[c] + k0, &lA[(wave * 16 + c * 8) * 64]);
            gld_lds16(bsrc[c] + k0, &lB[(wave * 16 + c * 8) * 64]);
        }
        __syncthreads();
#pragma unroll
        for (int kk = 0; kk < 2; kk++) {
            int slot = ((kk * 4 + quad) ^ sw) * 8;
            short8 a[2], b[2];
#pragma unroll
            for (int i = 0; i < 2; i++) {
                a[i] = *(const short8*)&lA[(wm * 32 + i * 16 + lm) * 64 + slot];
                b[i] = *(const short8*)&lB[(wn * 32 + i * 16 + lm) * 64 + slot];
            }
#pragma unroll
            for (int i = 0; i < 2; i++)
#pragma unroll
                for (int j = 0; j < 2; j++)
                    acc[i][j] = __builtin_amdgcn_mfma_f32_16x16x32_bf16(a[i], b[j], acc[i][j], 0, 0, 0);
        }
    }
#pragma unroll
    for (int j = 0; j < 2; j++) {
        int col = tile_n * 64 + wn * 32 + j * 16 + lm;
        float bias = b1[e * N + col];
#pragma unroll
        for (int i = 0; i < 2; i++)
#pragma unroll
            for (int r = 0; r < 4; r++) {
                int row = tile_m * 64 + wm * 32 + i * 16 + quad * 4 + r;
                float v = acc[i][j][r] + bias;
                hbuf[(size_t)row * N + col] = f2b(fmaxf(v, 0.f));
            }
    }
}

// ---------------- GEMM2: out[tok[row]] = (h[row]@W2t[e]^T + b2[e])*gate[row] ----------------
// 64x64 tile, 4 waves, per-wave 32x32 quadrant. W2t: [E][D][H]. grid (D/64, MAXT64).
__global__ __launch_bounds__(256) void gemm2_kernel(
    const bf16_t* __restrict__ hbuf, const bf16_t* __restrict__ W2t,
    const float* __restrict__ b2, const int* __restrict__ tile_expert,
    const int* __restrict__ tok_of_row, const float* __restrict__ gate_of_row,
    float* __restrict__ out) {
    constexpr int K = HDIM, N = DDIM;
    int tile_n = blockIdx.x, tile_m = blockIdx.y;
    int e = tile_expert[tile_m];
    if (e < 0) return;
    __shared__ bf16_t lA[64 * 64];
    __shared__ bf16_t lB[64 * 64];
    int tid = threadIdx.x, wave = tid >> 6, lane = tid & 63;
    int sc = (lane & 7) ^ ((lane >> 3) & 7);
    const bf16_t* asrc[2]; const bf16_t* bsrc[2];
#pragma unroll
    for (int c = 0; c < 2; c++) {
        int rr = wave * 16 + c * 8 + (lane >> 3);
        asrc[c] = hbuf + (size_t)(tile_m * 64 + rr) * K + sc * 8;
        bsrc[c] = W2t + (size_t)e * N * K + (size_t)(tile_n * 64 + rr) * K + sc * 8;
    }
    f32x4 acc[2][2];
#pragma unroll
    for (int i = 0; i < 2; i++)
#pragma unroll
        for (int j = 0; j < 2; j++) acc[i][j] = {0.f, 0.f, 0.f, 0.f};
    int wm = wave >> 1, wn = wave & 1;
    int lm = lane & 15, quad = lane >> 4;
    int sw = lm & 7;

    for (int k0 = 0; k0 < K; k0 += 64) {
        __syncthreads();
#pragma unroll
        for (int c = 0; c < 2; c++) {
            gld_lds16(asrc[c] + k0, &lA[(wave * 16 + c * 8) * 64]);
            gld_lds16(bsrc[c] + k0, &lB[(wave * 16 + c * 8) * 64]);
        }
        __syncthreads();
#pragma unroll
        for (int kk = 0; kk < 2; kk++) {
            int slot = ((kk * 4 + quad) ^ sw) * 8;
            short8 a[2], b[2];
#pragma unroll
            for (int i = 0; i < 2; i++) {
                a[i] = *(const short8*)&lA[(wm * 32 + i * 16 + lm) * 64 + slot];
                b[i] = *(const short8*)&lB[(wn * 32 + i * 16 + lm) * 64 + slot];
            }
#pragma unroll
            for (int i = 0; i < 2; i++)
#pragma unroll
                for (int j = 0; j < 2; j++)
                    acc[i][j] = __builtin_amdgcn_mfma_f32_16x16x32_bf16(a[i], b[j], acc[i][j], 0, 0, 0);
        }
    }
#pragma unroll
    for (int j = 0; j < 2; j++) {
        int col = tile_n * 64 + wn * 32 + j * 16 + lm;
        float bias = b2[e * N + col];
#pragma unroll
        for (int i = 0; i < 2; i++)
#pragma unroll
            for (int r = 0; r < 4; r++) {
                int row = tile_m * 64 + wm * 32 + i * 16 + quad * 4 + r;
                int tok = tok_of_row[row];
                if (tok >= 0) {
                    float v = (acc[i][j][r] + bias) * gate_of_row[row];
                    out[(size_t)tok * N + col] = v;   // fp32 store
                }
            }
    }
}

extern "C" void kernel_launch(void* const* d_in, const int* in_sizes, int n_in,
                              void* d_out, int out_size, void* d_ws, size_t ws_size,
                              hipStream_t stream) {
    const float* x  = (const float*)d_in[0];
    const float* Wr = (const float*)d_in[1];
    const float* br = (const float*)d_in[2];
    const float* W1 = (const float*)d_in[3];
    const float* b1 = (const float*)d_in[4];
    const float* W2 = (const float*)d_in[5];
    const float* b2 = (const float*)d_in[6];
    float* out = (float*)d_out;
    char* ws = (char*)d_ws;

    // ws layout (bytes)
    int*    counts      = (int*)(ws + 0);        // 32 B (zeroed)
    int*    cursor      = (int*)(ws + 32);       // 32 B (zeroed)
    int*    pad_off     = (int*)(ws + 64);       // 32 B
    int*    tile_expert = (int*)(ws + 96);       // 544 B (MAXT64)
    int*    expert_id   = (int*)(ws + 1024);     // 32 KiB
    float*  gate        = (float*)(ws + 33792);  // 32 KiB
    int*    tok_of_row  = (int*)(ws + 66560);    // 34816 B (memset -1)
    float*  gate_of_row = (float*)(ws + 101376); // 34816 B
    bf16_t* hbuf        = (bf16_t*)(ws + 136192);    // 8704*2048*2 = 35,651,584
    bf16_t* W1t         = (bf16_t*)(ws + 35787776);  // 33,554,432
    bf16_t* W2t         = (bf16_t*)(ws + 69342208);  // 33,554,432
    bf16_t* xbf         = (bf16_t*)(ws + 102896640); // 16,777,216 -> ends 119,673,856
    // total ~120 MB

    hipMemsetAsync(counts, 0, 64, stream);                  // counts + cursor
    hipMemsetAsync(tok_of_row, 0xFF, ROWSP * 4, stream);    // tok_of_row = -1

    prep_kernel<<<512 + 8192, 256, 0, stream>>>(x, Wr, br, expert_id, gate, counts, xbf,
                                                W1, W2, W1t, W2t);
    scan_kernel<<<1, 64, 0, stream>>>(counts, pad_off, tile_expert);
    scatter_kernel<<<T_TOK / 256, 256, 0, stream>>>(expert_id, gate, pad_off, cursor,
                                                    tok_of_row, gate_of_row);
    gemm1_kernel<<<dim3(HDIM / 64, MAXT64), 256, 0, stream>>>(xbf, W1t, b1, tile_expert,
                                                              tok_of_row, hbuf);
    gemm2_kernel<<<dim3(DDIM / 64, MAXT64), 256, 0, stream>>>(hbuf, W2t, b2, tile_expert,
                                                              tok_of_row, gate_of_row, out);
}

// Round 9
// 379.389 us; speedup vs baseline: 1.0188x; 1.0188x over previous
//
#include <hip/hip_runtime.h>
#include <hip/hip_bf16.h>
#include <stdint.h>

// B=4 S=2048 D=1024 H=2048 E=8 ; T = 8192 tokens, top-1 MoE.
// Inputs FLOAT32, output FLOAT32; GEMM compute in bf16 MFMA (fp32 accum).
// Round 15: revert R8 fusion (VGPR-capped the transpose branch: 112us vs 94
// serial). R7 structure restored (separate router/transpose/GEMMs, 64x64
// GEMM tiles) + ONE change: XCD-aware block swizzle in both GEMMs.
// Evidence: gemm2 FETCH 152MB vs 69MB cold minimum (2.2x overfetch) because
// the 16 tile_n blocks sharing an A-panel round-robin across 8 XCD L2s.
// Swizzle: xcd = bid%8 owns a contiguous chunk (tile_n fastest, then tile_m)
// -> A-panel fetched once per XCD, B-panels reused across same-expert tile_m.
// Grids divisible by 8 (4352, 2176) -> bijective map.

typedef unsigned short bf16_t;
typedef short short8 __attribute__((ext_vector_type(8)));
typedef float f32x4 __attribute__((ext_vector_type(4)));

#define T_TOK 8192
#define DDIM 1024
#define HDIM 2048
#define NEXP 8
#define MAXT64 136          // sum ceil(count_e/64) <= 8192/64 + 8 = 136
#define ROWSP (MAXT64 * 64) // 8704 padded row space

__device__ __forceinline__ bf16_t f2b(float f) {
    unsigned int x = __builtin_bit_cast(unsigned int, f);
    unsigned int r = x + 0x7fffu + ((x >> 16) & 1u);   // RNE
    return (bf16_t)(r >> 16);
}
__device__ __forceinline__ void gld_lds16(const bf16_t* src, bf16_t* dst) {
    // per-lane global src, wave-uniform LDS base; lane L writes at dst + L*16B
    __builtin_amdgcn_global_load_lds((const __attribute__((address_space(1))) void*)src,
                                     (__attribute__((address_space(3))) void*)dst, 16, 0, 0);
}

// ---------------- router: Wr in VGPRs, 4 tokens/wave, fused x->bf16 ----------------
__global__ __launch_bounds__(256) void router_kernel(
    const float* __restrict__ x, const float* __restrict__ Wr,
    const float* __restrict__ br, int* __restrict__ expert_id,
    float* __restrict__ gate, int* __restrict__ counts,
    bf16_t* __restrict__ xbf) {
    __shared__ int hcnt[NEXP];
    int tid = threadIdx.x, wave = tid >> 6, lane = tid & 63;
    if (tid < NEXP) hcnt[tid] = 0;
    __syncthreads();

    float w[4][4][NEXP];
#pragma unroll
    for (int i = 0; i < 4; i++)
#pragma unroll
        for (int j = 0; j < 4; j++) {
            const float* p = Wr + (size_t)(i * 256 + lane * 4 + j) * NEXP;
            float4 a = *(const float4*)p;
            float4 b = *(const float4*)(p + 4);
            w[i][j][0] = a.x; w[i][j][1] = a.y; w[i][j][2] = a.z; w[i][j][3] = a.w;
            w[i][j][4] = b.x; w[i][j][5] = b.y; w[i][j][6] = b.z; w[i][j][7] = b.w;
        }

    int t0 = (blockIdx.x * 4 + wave) * 4;
#pragma unroll
    for (int tt = 0; tt < 4; tt++) {
        int t = t0 + tt;
        float acc[NEXP];
#pragma unroll
        for (int e = 0; e < NEXP; e++) acc[e] = 0.f;
#pragma unroll
        for (int i = 0; i < 4; i++) {
            const float* xp = x + (size_t)t * DDIM + i * 256 + lane * 4;
            float4 xv = *(const float4*)xp;
            bf16_t tmp[4] = {f2b(xv.x), f2b(xv.y), f2b(xv.z), f2b(xv.w)};
            *(uint2*)(xbf + (size_t)t * DDIM + i * 256 + lane * 4) = *(uint2*)tmp;
            float xs[4] = {xv.x, xv.y, xv.z, xv.w};
#pragma unroll
            for (int j = 0; j < 4; j++)
#pragma unroll
                for (int e = 0; e < NEXP; e++) acc[e] += xs[j] * w[i][j][e];
        }
#pragma unroll
        for (int off = 32; off; off >>= 1)
#pragma unroll
            for (int e = 0; e < NEXP; e++) acc[e] += __shfl_xor(acc[e], off);
        if (lane == 0) {
            float l[NEXP];
#pragma unroll
            for (int e = 0; e < NEXP; e++) l[e] = acc[e] + br[e];
            int best = 0; float bm = l[0];
#pragma unroll
            for (int e = 1; e < NEXP; e++) if (l[e] > bm) { bm = l[e]; best = e; }
            float s = 0.f;
#pragma unroll
            for (int e = 0; e < NEXP; e++) s += __expf(l[e] - bm);
            expert_id[t] = best;
            gate[t] = 1.0f / s;      // softmax prob of the argmax expert
            atomicAdd(&hcnt[best], 1);
        }
    }
    __syncthreads();
    if (tid < NEXP) atomicAdd(&counts[tid], hcnt[tid]);
}

// ---------------- scan: 64-aligned segment offsets + 64-tile->expert map ----------------
__global__ __launch_bounds__(64) void scan_kernel(const int* __restrict__ counts,
                                                  int* __restrict__ pad_off,
                                                  int* __restrict__ tile_expert) {
    if (threadIdx.x == 0) {
        int rowoff = 0, t = 0;
        for (int e = 0; e < NEXP; e++) {
            pad_off[e] = rowoff;
            int nt = (counts[e] + 63) >> 6;
            rowoff += nt << 6;
            for (int i = 0; i < nt; i++) tile_expert[t++] = e;
        }
        while (t < MAXT64) tile_expert[t++] = -1;
    }
}

// ---------------- scatter: build row->token maps ----------------
__global__ __launch_bounds__(256) void scatter_kernel(
    const int* __restrict__ expert_id, const float* __restrict__ gate,
    const int* __restrict__ pad_off, int* __restrict__ cursor,
    int* __restrict__ tok_of_row, float* __restrict__ gate_of_row) {
    int t = blockIdx.x * 256 + threadIdx.x;
    int e = expert_id[t];
    int p = atomicAdd(&cursor[e], 1);
    int row = pad_off[e] + p;
    tok_of_row[row] = t;
    gate_of_row[row] = gate[t];
}

// ------------- fused fp32->bf16 transpose of W1 (z<8) and W2 (z>=8) -------------
// LDS: rows of 4-elem (8B) chunks, chunk slot XOR-swizzled by row&15.
// Read: 4x ds_read_b64 per thread (4x4 sub-block), register transpose,
// coalesced uint2 column writes. Conflicts 7.34M -> 786K (measured R7).
__global__ __launch_bounds__(256) void transpose_all_kernel(
    const float* __restrict__ W1, const float* __restrict__ W2,
    bf16_t* __restrict__ W1t, bf16_t* __restrict__ W2t) {
    __shared__ bf16_t tile[64][72];   // stride 36 words; swizzle does the spreading
    int z = blockIdx.z;
    const float* inp; bf16_t* outp; int R, C;
    if (z < 8) { inp = W1 + (size_t)z * DDIM * HDIM; outp = W1t + (size_t)z * DDIM * HDIM;
                 R = DDIM; C = HDIM; }
    else       { inp = W2 + (size_t)(z - 8) * HDIM * DDIM; outp = W2t + (size_t)(z - 8) * HDIM * DDIM;
                 R = HDIM; C = DDIM; }
    int ctiles = C >> 6;
    int cx = blockIdx.x % ctiles, ry = blockIdx.x / ctiles;
    int r0 = ry * 64, c0 = cx * 64;
    int tid = threadIdx.x;
#pragma unroll
    for (int v = tid; v < 1024; v += 256) {     // 64 rows x 16 chunks of 4 floats
        int r = v >> 4, ch = v & 15;
        float4 f = *(const float4*)(inp + (size_t)(r0 + r) * C + c0 + ch * 4);
        bf16_t tmp[4] = {f2b(f.x), f2b(f.y), f2b(f.z), f2b(f.w)};
        *(uint2*)&tile[r][(ch ^ (r & 15)) * 4] = *(uint2*)tmp;
    }
    __syncthreads();
    {
        int rb = tid & 15, cb = tid >> 4;       // 16x16 grid of 4x4 sub-blocks
        uint2 m[4];
#pragma unroll
        for (int i = 0; i < 4; i++) {
            int r = rb * 4 + i;
            m[i] = *(const uint2*)&tile[r][(cb ^ (r & 15)) * 4];
        }
        uint32_t w0[4] = {m[0].x, m[1].x, m[2].x, m[3].x};  // cols 0,1 of the 4 rows
        uint32_t w1[4] = {m[0].y, m[1].y, m[2].y, m[3].y};  // cols 2,3
#pragma unroll
        for (int j = 0; j < 4; j++) {
            const uint32_t* w = (j < 2) ? w0 : w1;
            uint32_t o0, o1;
            if (j & 1) { o0 = (w[0] >> 16) | (w[1] & 0xffff0000u);
                         o1 = (w[2] >> 16) | (w[3] & 0xffff0000u); }
            else       { o0 = (w[0] & 0xffffu) | (w[1] << 16);
                         o1 = (w[2] & 0xffffu) | (w[3] << 16); }
            uint2 o; o.x = o0; o.y = o1;
            *(uint2*)(outp + (size_t)(c0 + cb * 4 + j) * R + r0 + rb * 4) = o;
        }
    }
}

// ---------------- GEMM1: h[row][H] = relu(xbf[tok[row]] @ W1t[e]^T + b1[e]) ----------------
// 64x64 tile, 4 waves, per-wave 32x32 quadrant (acc 2x2). Single-buffer,
// XOR-swizzled LDS. W1t: [E][H][D]. Flat grid 4352 with XCD-chunk swizzle:
// xcd = bid%8 owns 544 consecutive work items (17 full tile_m rows).
__global__ __launch_bounds__(256) void gemm1_kernel(
    const bf16_t* __restrict__ x, const bf16_t* __restrict__ W1t,
    const float* __restrict__ b1, const int* __restrict__ tile_expert,
    const int* __restrict__ tok_of_row, bf16_t* __restrict__ hbuf) {
    constexpr int K = DDIM, N = HDIM;
    constexpr int NT_N = N / 64;                  // 32 n-tiles
    constexpr int CHUNK = (NT_N * MAXT64) / 8;    // 544 per XCD
    int bid = blockIdx.x;
    int swz = (bid & 7) * CHUNK + (bid >> 3);
    int tile_n = swz % NT_N, tile_m = swz / NT_N;
    int e = tile_expert[tile_m];
    if (e < 0) return;
    __shared__ bf16_t lA[64 * 64];   // 8 KiB
    __shared__ bf16_t lB[64 * 64];   // 8 KiB
    int tid = threadIdx.x, wave = tid >> 6, lane = tid & 63;
    // staging: lane L covers row (base + L>>3), fetches source chunk (L&7)^((L>>3)&7)
    int sc = (lane & 7) ^ ((lane >> 3) & 7);
    const bf16_t* asrc[2]; const bf16_t* bsrc[2];
#pragma unroll
    for (int c = 0; c < 2; c++) {
        int rr = wave * 16 + c * 8 + (lane >> 3);
        int tok = tok_of_row[tile_m * 64 + rr];
        if (tok < 0) tok = 0;   // padded row: read any valid row; masked downstream
        asrc[c] = x + (size_t)tok * K + sc * 8;
        bsrc[c] = W1t + (size_t)e * N * K + (size_t)(tile_n * 64 + rr) * K + sc * 8;
    }
    f32x4 acc[2][2];
#pragma unroll
    for (int i = 0; i < 2; i++)
#pragma unroll
        for (int j = 0; j < 2; j++) acc[i][j] = {0.f, 0.f, 0.f, 0.f};
    int wm = wave >> 1, wn = wave & 1;
    int lm = lane & 15, quad = lane >> 4;
    int sw = lm & 7;   // row&7 for all fragment rows (row = mult16 + lm)

    for (int k0 = 0; k0 < K; k0 += 64) {
        __syncthreads();
#pragma unroll
        for (int c = 0; c < 2; c++) {
            gld_lds16(asrc[c] + k0, &lA[(wave * 16 + c * 8) * 64]);
            gld_lds16(bsrc[c] + k0, &lB[(wave * 16 + c * 8) * 64]);
        }
        __syncthreads();
#pragma unroll
        for (int kk = 0; kk < 2; kk++) {
            int slot = ((kk * 4 + quad) ^ sw) * 8;
            short8 a[2], b[2];
#pragma unroll
            for (int i = 0; i < 2; i++) {
                a[i] = *(const short8*)&lA[(wm * 32 + i * 16 + lm) * 64 + slot];
                b[i] = *(const short8*)&lB[(wn * 32 + i * 16 + lm) * 64 + slot];
            }
#pragma unroll
            for (int i = 0; i < 2; i++)
#pragma unroll
                for (int j = 0; j < 2; j++)
                    acc[i][j] = __builtin_amdgcn_mfma_f32_16x16x32_bf16(a[i], b[j], acc[i][j], 0, 0, 0);
        }
    }
#pragma unroll
    for (int j = 0; j < 2; j++) {
        int col = tile_n * 64 + wn * 32 + j * 16 + lm;
        float bias = b1[e * N + col];
#pragma unroll
        for (int i = 0; i < 2; i++)
#pragma unroll
            for (int r = 0; r < 4; r++) {
                int row = tile_m * 64 + wm * 32 + i * 16 + quad * 4 + r;
                float v = acc[i][j][r] + bias;
                hbuf[(size_t)row * N + col] = f2b(fmaxf(v, 0.f));
            }
    }
}

// ---------------- GEMM2: out[tok[row]] = (h[row]@W2t[e]^T + b2[e])*gate[row] ----------------
// 64x64 tile, 4 waves, per-wave 32x32 quadrant. W2t: [E][D][H].
// Flat grid 2176 with XCD-chunk swizzle (272 per XCD = 17 full tile_m rows).
__global__ __launch_bounds__(256) void gemm2_kernel(
    const bf16_t* __restrict__ hbuf, const bf16_t* __restrict__ W2t,
    const float* __restrict__ b2, const int* __restrict__ tile_expert,
    const int* __restrict__ tok_of_row, const float* __restrict__ gate_of_row,
    float* __restrict__ out) {
    constexpr int K = HDIM, N = DDIM;
    constexpr int NT_N = N / 64;                  // 16 n-tiles
    constexpr int CHUNK = (NT_N * MAXT64) / 8;    // 272 per XCD
    int bid = blockIdx.x;
    int swz = (bid & 7) * CHUNK + (bid >> 3);
    int tile_n = swz % NT_N, tile_m = swz / NT_N;
    int e = tile_expert[tile_m];
    if (e < 0) return;
    __shared__ bf16_t lA[64 * 64];
    __shared__ bf16_t lB[64 * 64];
    int tid = threadIdx.x, wave = tid >> 6, lane = tid & 63;
    int sc = (lane & 7) ^ ((lane >> 3) & 7);
    const bf16_t* asrc[2]; const bf16_t* bsrc[2];
#pragma unroll
    for (int c = 0; c < 2; c++) {
        int rr = wave * 16 + c * 8 + (lane >> 3);
        asrc[c] = hbuf + (size_t)(tile_m * 64 + rr) * K + sc * 8;
        bsrc[c] = W2t + (size_t)e * N * K + (size_t)(tile_n * 64 + rr) * K + sc * 8;
    }
    f32x4 acc[2][2];
#pragma unroll
    for (int i = 0; i < 2; i++)
#pragma unroll
        for (int j = 0; j < 2; j++) acc[i][j] = {0.f, 0.f, 0.f, 0.f};
    int wm = wave >> 1, wn = wave & 1;
    int lm = lane & 15, quad = lane >> 4;
    int sw = lm & 7;

    for (int k0 = 0; k0 < K; k0 += 64) {
        __syncthreads();
#pragma unroll
        for (int c = 0; c < 2; c++) {
            gld_lds16(asrc[c] + k0, &lA[(wave * 16 + c * 8) * 64]);
            gld_lds16(bsrc[c] + k0, &lB[(wave * 16 + c * 8) * 64]);
        }
        __syncthreads();
#pragma unroll
        for (int kk = 0; kk < 2; kk++) {
            int slot = ((kk * 4 + quad) ^ sw) * 8;
            short8 a[2], b[2];
#pragma unroll
            for (int i = 0; i < 2; i++) {
                a[i] = *(const short8*)&lA[(wm * 32 + i * 16 + lm) * 64 + slot];
                b[i] = *(const short8*)&lB[(wn * 32 + i * 16 + lm) * 64 + slot];
            }
#pragma unroll
            for (int i = 0; i < 2; i++)
#pragma unroll
                for (int j = 0; j < 2; j++)
                    acc[i][j] = __builtin_amdgcn_mfma_f32_16x16x32_bf16(a[i], b[j], acc[i][j], 0, 0, 0);
        }
    }
#pragma unroll
    for (int j = 0; j < 2; j++) {
        int col = tile_n * 64 + wn * 32 + j * 16 + lm;
        float bias = b2[e * N + col];
#pragma unroll
        for (int i = 0; i < 2; i++)
#pragma unroll
            for (int r = 0; r < 4; r++) {
                int row = tile_m * 64 + wm * 32 + i * 16 + quad * 4 + r;
                int tok = tok_of_row[row];
                if (tok >= 0) {
                    float v = (acc[i][j][r] + bias) * gate_of_row[row];
                    out[(size_t)tok * N + col] = v;   // fp32 store
                }
            }
    }
}

extern "C" void kernel_launch(void* const* d_in, const int* in_sizes, int n_in,
                              void* d_out, int out_size, void* d_ws, size_t ws_size,
                              hipStream_t stream) {
    const float* x  = (const float*)d_in[0];
    const float* Wr = (const float*)d_in[1];
    const float* br = (const float*)d_in[2];
    const float* W1 = (const float*)d_in[3];
    const float* b1 = (const float*)d_in[4];
    const float* W2 = (const float*)d_in[5];
    const float* b2 = (const float*)d_in[6];
    float* out = (float*)d_out;
    char* ws = (char*)d_ws;

    // ws layout (bytes)
    int*    counts      = (int*)(ws + 0);        // 32 B (zeroed)
    int*    cursor      = (int*)(ws + 32);       // 32 B (zeroed)
    int*    pad_off     = (int*)(ws + 64);       // 32 B
    int*    tile_expert = (int*)(ws + 96);       // 544 B (MAXT64)
    int*    expert_id   = (int*)(ws + 1024);     // 32 KiB
    float*  gate        = (float*)(ws + 33792);  // 32 KiB
    int*    tok_of_row  = (int*)(ws + 66560);    // 34816 B (memset -1)
    float*  gate_of_row = (float*)(ws + 101376); // 34816 B
    bf16_t* hbuf        = (bf16_t*)(ws + 136192);    // 8704*2048*2 = 35,651,584
    bf16_t* W1t         = (bf16_t*)(ws + 35787776);  // 33,554,432
    bf16_t* W2t         = (bf16_t*)(ws + 69342208);  // 33,554,432
    bf16_t* xbf         = (bf16_t*)(ws + 102896640); // 16,777,216 -> ends 119,673,856
    // total ~120 MB

    hipMemsetAsync(counts, 0, 64, stream);                  // counts + cursor
    hipMemsetAsync(tok_of_row, 0xFF, ROWSP * 4, stream);    // tok_of_row = -1

    router_kernel<<<512, 256, 0, stream>>>(x, Wr, br, expert_id, gate, counts, xbf);
    scan_kernel<<<1, 64, 0, stream>>>(counts, pad_off, tile_expert);
    scatter_kernel<<<T_TOK / 256, 256, 0, stream>>>(expert_id, gate, pad_off, cursor,
                                                    tok_of_row, gate_of_row);
    transpose_all_kernel<<<dim3(512, 1, 16), 256, 0, stream>>>(W1, W2, W1t, W2t);
    gemm1_kernel<<<(HDIM / 64) * MAXT64, 256, 0, stream>>>(xbf, W1t, b1, tile_expert,
                                                           tok_of_row, hbuf);
    gemm2_kernel<<<(DDIM / 64) * MAXT64, 256, 0, stream>>>(hbuf, W2t, b2, tile_expert,
                                                           tok_of_row, gate_of_row, out);
}

// Round 10
// 374.585 us; speedup vs baseline: 1.0319x; 1.0128x over previous
//
#include <hip/hip_runtime.h>
#include <hip/hip_bf16.h>
#include <stdint.h>

// B=4 S=2048 D=1024 H=2048 E=8 ; T = 8192 tokens, top-1 MoE.
// Inputs FLOAT32, output FLOAT32; GEMM compute in bf16 MFMA (fp32 accum).
// Round 16: R9 kept (64x64 XCD-swizzled GEMMs, best 379us) + transpose
// rebuilt at 128x128 granularity: 512B row reads, 16B LDS chunks
// (ds_write_b128/ds_read_b128, slot = ch ^ (r>>3) swizzle -- conflict-free
// both phases at the 8-rounds/bank hardware minimum), per-thread 8x8
// register transpose, 16B stores in 256B contiguous segments.
// Old 64x64 version was granularity-bound (256B reads, 8B stores): 69us
// flat across conflict fixes. Blocks 8192 -> 2048, LDS 32KB.

typedef unsigned short bf16_t;
typedef short short8 __attribute__((ext_vector_type(8)));
typedef float f32x4 __attribute__((ext_vector_type(4)));

#define T_TOK 8192
#define DDIM 1024
#define HDIM 2048
#define NEXP 8
#define MAXT64 136          // sum ceil(count_e/64) <= 8192/64 + 8 = 136
#define ROWSP (MAXT64 * 64) // 8704 padded row space

__device__ __forceinline__ bf16_t f2b(float f) {
    unsigned int x = __builtin_bit_cast(unsigned int, f);
    unsigned int r = x + 0x7fffu + ((x >> 16) & 1u);   // RNE
    return (bf16_t)(r >> 16);
}
__device__ __forceinline__ void gld_lds16(const bf16_t* src, bf16_t* dst) {
    // per-lane global src, wave-uniform LDS base; lane L writes at dst + L*16B
    __builtin_amdgcn_global_load_lds((const __attribute__((address_space(1))) void*)src,
                                     (__attribute__((address_space(3))) void*)dst, 16, 0, 0);
}

// ---------------- router: Wr in VGPRs, 4 tokens/wave, fused x->bf16 ----------------
__global__ __launch_bounds__(256) void router_kernel(
    const float* __restrict__ x, const float* __restrict__ Wr,
    const float* __restrict__ br, int* __restrict__ expert_id,
    float* __restrict__ gate, int* __restrict__ counts,
    bf16_t* __restrict__ xbf) {
    __shared__ int hcnt[NEXP];
    int tid = threadIdx.x, wave = tid >> 6, lane = tid & 63;
    if (tid < NEXP) hcnt[tid] = 0;
    __syncthreads();

    float w[4][4][NEXP];
#pragma unroll
    for (int i = 0; i < 4; i++)
#pragma unroll
        for (int j = 0; j < 4; j++) {
            const float* p = Wr + (size_t)(i * 256 + lane * 4 + j) * NEXP;
            float4 a = *(const float4*)p;
            float4 b = *(const float4*)(p + 4);
            w[i][j][0] = a.x; w[i][j][1] = a.y; w[i][j][2] = a.z; w[i][j][3] = a.w;
            w[i][j][4] = b.x; w[i][j][5] = b.y; w[i][j][6] = b.z; w[i][j][7] = b.w;
        }

    int t0 = (blockIdx.x * 4 + wave) * 4;
#pragma unroll
    for (int tt = 0; tt < 4; tt++) {
        int t = t0 + tt;
        float acc[NEXP];
#pragma unroll
        for (int e = 0; e < NEXP; e++) acc[e] = 0.f;
#pragma unroll
        for (int i = 0; i < 4; i++) {
            const float* xp = x + (size_t)t * DDIM + i * 256 + lane * 4;
            float4 xv = *(const float4*)xp;
            bf16_t tmp[4] = {f2b(xv.x), f2b(xv.y), f2b(xv.z), f2b(xv.w)};
            *(uint2*)(xbf + (size_t)t * DDIM + i * 256 + lane * 4) = *(uint2*)tmp;
            float xs[4] = {xv.x, xv.y, xv.z, xv.w};
#pragma unroll
            for (int j = 0; j < 4; j++)
#pragma unroll
                for (int e = 0; e < NEXP; e++) acc[e] += xs[j] * w[i][j][e];
        }
#pragma unroll
        for (int off = 32; off; off >>= 1)
#pragma unroll
            for (int e = 0; e < NEXP; e++) acc[e] += __shfl_xor(acc[e], off);
        if (lane == 0) {
            float l[NEXP];
#pragma unroll
            for (int e = 0; e < NEXP; e++) l[e] = acc[e] + br[e];
            int best = 0; float bm = l[0];
#pragma unroll
            for (int e = 1; e < NEXP; e++) if (l[e] > bm) { bm = l[e]; best = e; }
            float s = 0.f;
#pragma unroll
            for (int e = 0; e < NEXP; e++) s += __expf(l[e] - bm);
            expert_id[t] = best;
            gate[t] = 1.0f / s;      // softmax prob of the argmax expert
            atomicAdd(&hcnt[best], 1);
        }
    }
    __syncthreads();
    if (tid < NEXP) atomicAdd(&counts[tid], hcnt[tid]);
}

// ---------------- scan: 64-aligned segment offsets + 64-tile->expert map ----------------
__global__ __launch_bounds__(64) void scan_kernel(const int* __restrict__ counts,
                                                  int* __restrict__ pad_off,
                                                  int* __restrict__ tile_expert) {
    if (threadIdx.x == 0) {
        int rowoff = 0, t = 0;
        for (int e = 0; e < NEXP; e++) {
            pad_off[e] = rowoff;
            int nt = (counts[e] + 63) >> 6;
            rowoff += nt << 6;
            for (int i = 0; i < nt; i++) tile_expert[t++] = e;
        }
        while (t < MAXT64) tile_expert[t++] = -1;
    }
}

// ---------------- scatter: build row->token maps ----------------
__global__ __launch_bounds__(256) void scatter_kernel(
    const int* __restrict__ expert_id, const float* __restrict__ gate,
    const int* __restrict__ pad_off, int* __restrict__ cursor,
    int* __restrict__ tok_of_row, float* __restrict__ gate_of_row) {
    int t = blockIdx.x * 256 + threadIdx.x;
    int e = expert_id[t];
    int p = atomicAdd(&cursor[e], 1);
    int row = pad_off[e] + p;
    tok_of_row[row] = t;
    gate_of_row[row] = gate[t];
}

// ------------- fused fp32->bf16 transpose of W1 (z<8) and W2 (z>=8) -------------
// 128x128 tile. LDS rows of 16B chunks, slot = ch ^ (r>>3) (involution both
// phases; 8 rounds/bank = minimum). Phase 1: 2x float4 reads (512B/row
// across 16 threads), 8x f2b, ds_write_b128. Phase 2: per-thread 8x8
// sub-block via 8x ds_read_b128 (slot = cb^rb, uniform), register 8x8
// transpose (static-indexed), 8x uint4 stores in 256B contiguous segments.
__global__ __launch_bounds__(256) void transpose_all_kernel(
    const float* __restrict__ W1, const float* __restrict__ W2,
    bf16_t* __restrict__ W1t, bf16_t* __restrict__ W2t) {
    __shared__ bf16_t tile[128][128];   // 32 KiB; swizzle does the spreading
    int z = blockIdx.z;
    const float* inp; bf16_t* outp; int R, C;
    if (z < 8) { inp = W1 + (size_t)z * DDIM * HDIM; outp = W1t + (size_t)z * DDIM * HDIM;
                 R = DDIM; C = HDIM; }
    else       { inp = W2 + (size_t)(z - 8) * HDIM * DDIM; outp = W2t + (size_t)(z - 8) * HDIM * DDIM;
                 R = HDIM; C = DDIM; }
    int ctiles = C >> 7;
    int cx = blockIdx.x % ctiles, ry = blockIdx.x / ctiles;
    int r0 = ry * 128, c0 = cx * 128;
    int tid = threadIdx.x;
#pragma unroll
    for (int it = 0; it < 8; it++) {    // 128 rows x 16 chunks of 8 floats
        int v = tid + it * 256;
        int r = v >> 4, ch = v & 15;
        const float* p = inp + (size_t)(r0 + r) * C + c0 + ch * 8;
        float4 f0 = *(const float4*)p;
        float4 f1 = *(const float4*)(p + 4);
        bf16_t tmp[8] = {f2b(f0.x), f2b(f0.y), f2b(f0.z), f2b(f0.w),
                         f2b(f1.x), f2b(f1.y), f2b(f1.z), f2b(f1.w)};
        int slot = ch ^ ((r >> 3) & 15);
        *(uint4*)&tile[r][slot * 8] = *(uint4*)tmp;
    }
    __syncthreads();
    {
        int rb = tid & 15, cb = tid >> 4;   // 16x16 grid of 8x8 sub-blocks
        uint4 m[8];
#pragma unroll
        for (int i = 0; i < 8; i++) {
            int r = rb * 8 + i;
            int slot = cb ^ ((r >> 3) & 15);   // = cb ^ rb (constant per thread)
            m[i] = *(const uint4*)&tile[r][slot * 8];
        }
#pragma unroll
        for (int j = 0; j < 8; j++) {
            uint32_t o[4];
#pragma unroll
            for (int w = 0; w < 4; w++) {
                uint32_t a = ((const uint32_t*)&m[2 * w])[j >> 1];
                uint32_t b = ((const uint32_t*)&m[2 * w + 1])[j >> 1];
                o[w] = (j & 1) ? ((a >> 16) | (b & 0xffff0000u))
                               : ((a & 0xffffu) | (b << 16));
            }
            *(uint4*)(outp + (size_t)(c0 + cb * 8 + j) * R + r0 + rb * 8) = *(uint4*)o;
        }
    }
}

// ---------------- GEMM1: h[row][H] = relu(xbf[tok[row]] @ W1t[e]^T + b1[e]) ----------------
// 64x64 tile, 4 waves, per-wave 32x32 quadrant (acc 2x2). Single-buffer,
// XOR-swizzled LDS. W1t: [E][H][D]. Flat grid 4352 with XCD-chunk swizzle:
// xcd = bid%8 owns 544 consecutive work items (17 full tile_m rows).
__global__ __launch_bounds__(256) void gemm1_kernel(
    const bf16_t* __restrict__ x, const bf16_t* __restrict__ W1t,
    const float* __restrict__ b1, const int* __restrict__ tile_expert,
    const int* __restrict__ tok_of_row, bf16_t* __restrict__ hbuf) {
    constexpr int K = DDIM, N = HDIM;
    constexpr int NT_N = N / 64;                  // 32 n-tiles
    constexpr int CHUNK = (NT_N * MAXT64) / 8;    // 544 per XCD
    int bid = blockIdx.x;
    int swz = (bid & 7) * CHUNK + (bid >> 3);
    int tile_n = swz % NT_N, tile_m = swz / NT_N;
    int e = tile_expert[tile_m];
    if (e < 0) return;
    __shared__ bf16_t lA[64 * 64];   // 8 KiB
    __shared__ bf16_t lB[64 * 64];   // 8 KiB
    int tid = threadIdx.x, wave = tid >> 6, lane = tid & 63;
    // staging: lane L covers row (base + L>>3), fetches source chunk (L&7)^((L>>3)&7)
    int sc = (lane & 7) ^ ((lane >> 3) & 7);
    const bf16_t* asrc[2]; const bf16_t* bsrc[2];
#pragma unroll
    for (int c = 0; c < 2; c++) {
        int rr = wave * 16 + c * 8 + (lane >> 3);
        int tok = tok_of_row[tile_m * 64 + rr];
        if (tok < 0) tok = 0;   // padded row: read any valid row; masked downstream
        asrc[c] = x + (size_t)tok * K + sc * 8;
        bsrc[c] = W1t + (size_t)e * N * K + (size_t)(tile_n * 64 + rr) * K + sc * 8;
    }
    f32x4 acc[2][2];
#pragma unroll
    for (int i = 0; i < 2; i++)
#pragma unroll
        for (int j = 0; j < 2; j++) acc[i][j] = {0.f, 0.f, 0.f, 0.f};
    int wm = wave >> 1, wn = wave & 1;
    int lm = lane & 15, quad = lane >> 4;
    int sw = lm & 7;   // row&7 for all fragment rows (row = mult16 + lm)

    for (int k0 = 0; k0 < K; k0 += 64) {
        __syncthreads();
#pragma unroll
        for (int c = 0; c < 2; c++) {
            gld_lds16(asrc[c] + k0, &lA[(wave * 16 + c * 8) * 64]);
            gld_lds16(bsrc[c] + k0, &lB[(wave * 16 + c * 8) * 64]);
        }
        __syncthreads();
#pragma unroll
        for (int kk = 0; kk < 2; kk++) {
            int slot = ((kk * 4 + quad) ^ sw) * 8;
            short8 a[2], b[2];
#pragma unroll
            for (int i = 0; i < 2; i++) {
                a[i] = *(const short8*)&lA[(wm * 32 + i * 16 + lm) * 64 + slot];
                b[i] = *(const short8*)&lB[(wn * 32 + i * 16 + lm) * 64 + slot];
            }
#pragma unroll
            for (int i = 0; i < 2; i++)
#pragma unroll
                for (int j = 0; j < 2; j++)
                    acc[i][j] = __builtin_amdgcn_mfma_f32_16x16x32_bf16(a[i], b[j], acc[i][j], 0, 0, 0);
        }
    }
#pragma unroll
    for (int j = 0; j < 2; j++) {
        int col = tile_n * 64 + wn * 32 + j * 16 + lm;
        float bias = b1[e * N + col];
#pragma unroll
        for (int i = 0; i < 2; i++)
#pragma unroll
            for (int r = 0; r < 4; r++) {
                int row = tile_m * 64 + wm * 32 + i * 16 + quad * 4 + r;
                float v = acc[i][j][r] + bias;
                hbuf[(size_t)row * N + col] = f2b(fmaxf(v, 0.f));
            }
    }
}

// ---------------- GEMM2: out[tok[row]] = (h[row]@W2t[e]^T + b2[e])*gate[row] ----------------
// 64x64 tile, 4 waves, per-wave 32x32 quadrant. W2t: [E][D][H].
// Flat grid 2176 with XCD-chunk swizzle (272 per XCD = 17 full tile_m rows).
__global__ __launch_bounds__(256) void gemm2_kernel(
    const bf16_t* __restrict__ hbuf, const bf16_t* __restrict__ W2t,
    const float* __restrict__ b2, const int* __restrict__ tile_expert,
    const int* __restrict__ tok_of_row, const float* __restrict__ gate_of_row,
    float* __restrict__ out) {
    constexpr int K = HDIM, N = DDIM;
    constexpr int NT_N = N / 64;                  // 16 n-tiles
    constexpr int CHUNK = (NT_N * MAXT64) / 8;    // 272 per XCD
    int bid = blockIdx.x;
    int swz = (bid & 7) * CHUNK + (bid >> 3);
    int tile_n = swz % NT_N, tile_m = swz / NT_N;
    int e = tile_expert[tile_m];
    if (e < 0) return;
    __shared__ bf16_t lA[64 * 64];
    __shared__ bf16_t lB[64 * 64];
    int tid = threadIdx.x, wave = tid >> 6, lane = tid & 63;
    int sc = (lane & 7) ^ ((lane >> 3) & 7);
    const bf16_t* asrc[2]; const bf16_t* bsrc[2];
#pragma unroll
    for (int c = 0; c < 2; c++) {
        int rr = wave * 16 + c * 8 + (lane >> 3);
        asrc[c] = hbuf + (size_t)(tile_m * 64 + rr) * K + sc * 8;
        bsrc[c] = W2t + (size_t)e * N * K + (size_t)(tile_n * 64 + rr) * K + sc * 8;
    }
    f32x4 acc[2][2];
#pragma unroll
    for (int i = 0; i < 2; i++)
#pragma unroll
        for (int j = 0; j < 2; j++) acc[i][j] = {0.f, 0.f, 0.f, 0.f};
    int wm = wave >> 1, wn = wave & 1;
    int lm = lane & 15, quad = lane >> 4;
    int sw = lm & 7;

    for (int k0 = 0; k0 < K; k0 += 64) {
        __syncthreads();
#pragma unroll
        for (int c = 0; c < 2; c++) {
            gld_lds16(asrc[c] + k0, &lA[(wave * 16 + c * 8) * 64]);
            gld_lds16(bsrc[c] + k0, &lB[(wave * 16 + c * 8) * 64]);
        }
        __syncthreads();
#pragma unroll
        for (int kk = 0; kk < 2; kk++) {
            int slot = ((kk * 4 + quad) ^ sw) * 8;
            short8 a[2], b[2];
#pragma unroll
            for (int i = 0; i < 2; i++) {
                a[i] = *(const short8*)&lA[(wm * 32 + i * 16 + lm) * 64 + slot];
                b[i] = *(const short8*)&lB[(wn * 32 + i * 16 + lm) * 64 + slot];
            }
#pragma unroll
            for (int i = 0; i < 2; i++)
#pragma unroll
                for (int j = 0; j < 2; j++)
                    acc[i][j] = __builtin_amdgcn_mfma_f32_16x16x32_bf16(a[i], b[j], acc[i][j], 0, 0, 0);
        }
    }
#pragma unroll
    for (int j = 0; j < 2; j++) {
        int col = tile_n * 64 + wn * 32 + j * 16 + lm;
        float bias = b2[e * N + col];
#pragma unroll
        for (int i = 0; i < 2; i++)
#pragma unroll
            for (int r = 0; r < 4; r++) {
                int row = tile_m * 64 + wm * 32 + i * 16 + quad * 4 + r;
                int tok = tok_of_row[row];
                if (tok >= 0) {
                    float v = (acc[i][j][r] + bias) * gate_of_row[row];
                    out[(size_t)tok * N + col] = v;   // fp32 store
                }
            }
    }
}

extern "C" void kernel_launch(void* const* d_in, const int* in_sizes, int n_in,
                              void* d_out, int out_size, void* d_ws, size_t ws_size,
                              hipStream_t stream) {
    const float* x  = (const float*)d_in[0];
    const float* Wr = (const float*)d_in[1];
    const float* br = (const float*)d_in[2];
    const float* W1 = (const float*)d_in[3];
    const float* b1 = (const float*)d_in[4];
    const float* W2 = (const float*)d_in[5];
    const float* b2 = (const float*)d_in[6];
    float* out = (float*)d_out;
    char* ws = (char*)d_ws;

    // ws layout (bytes)
    int*    counts      = (int*)(ws + 0);        // 32 B (zeroed)
    int*    cursor      = (int*)(ws + 32);       // 32 B (zeroed)
    int*    pad_off     = (int*)(ws + 64);       // 32 B
    int*    tile_expert = (int*)(ws + 96);       // 544 B (MAXT64)
    int*    expert_id   = (int*)(ws + 1024);     // 32 KiB
    float*  gate        = (float*)(ws + 33792);  // 32 KiB
    int*    tok_of_row  = (int*)(ws + 66560);    // 34816 B (memset -1)
    float*  gate_of_row = (float*)(ws + 101376); // 34816 B
    bf16_t* hbuf        = (bf16_t*)(ws + 136192);    // 8704*2048*2 = 35,651,584
    bf16_t* W1t         = (bf16_t*)(ws + 35787776);  // 33,554,432
    bf16_t* W2t         = (bf16_t*)(ws + 69342208);  // 33,554,432
    bf16_t* xbf         = (bf16_t*)(ws + 102896640); // 16,777,216 -> ends 119,673,856
    // total ~120 MB

    hipMemsetAsync(counts, 0, 64, stream);                  // counts + cursor
    hipMemsetAsync(tok_of_row, 0xFF, ROWSP * 4, stream);    // tok_of_row = -1

    router_kernel<<<512, 256, 0, stream>>>(x, Wr, br, expert_id, gate, counts, xbf);
    scan_kernel<<<1, 64, 0, stream>>>(counts, pad_off, tile_expert);
    scatter_kernel<<<T_TOK / 256, 256, 0, stream>>>(expert_id, gate, pad_off, cursor,
                                                    tok_of_row, gate_of_row);
    transpose_all_kernel<<<dim3(128, 1, 16), 256, 0, stream>>>(W1, W2, W1t, W2t);
    gemm1_kernel<<<(HDIM / 64) * MAXT64, 256, 0, stream>>>(xbf, W1t, b1, tile_expert,
                                                           tok_of_row, hbuf);
    gemm2_kernel<<<(DDIM / 64) * MAXT64, 256, 0, stream>>>(hbuf, W2t, b2, tile_expert,
                                                           tok_of_row, gate_of_row, out);
}